// Round 2
// baseline (2814.345 us; speedup 1.0000x reference)
//
#include <hip/hip_runtime.h>

#define EMB 64
#define INDIM 140
#define NL 4
#define EPS 1e-5f

__device__ __forceinline__ float bnrelu(float v, float sum, float sq, float g, float be, float invN){
  float mu  = sum*invN;
  float var = fmaf(-mu, mu, sq*invN);
  float sc  = g * rsqrtf(var + EPS);
  return fmaxf(fmaf(v - mu, sc, be), 0.f);
}

// ---- fused: deg histogram + edge_attr moments (block-reduced, padded atomics) ----
__global__ __launch_bounds__(256) void k_pass1(const int* __restrict__ dst,
    const float* __restrict__ ea, int E, int* __restrict__ deg, float* __restrict__ est)
{
  __shared__ float ls[9];
  if (threadIdx.x < 9) ls[threadIdx.x] = 0.f;
  __syncthreads();
  int tid = blockIdx.x*blockDim.x + threadIdx.x;
  int stride = gridDim.x*blockDim.x;
  float a0=0,a1=0,a2=0,p00=0,p11=0,p22=0,p01=0,p02=0,p12=0;
  for (int e=tid;e<E;e+=stride){
    atomicAdd(&deg[dst[e]],1);
    float d0=ea[3*e+0], d1=ea[3*e+1], d2=ea[3*e+2];
    a0+=d0;a1+=d1;a2+=d2;
    p00=fmaf(d0,d0,p00); p11=fmaf(d1,d1,p11); p22=fmaf(d2,d2,p22);
    p01=fmaf(d0,d1,p01); p02=fmaf(d0,d2,p02); p12=fmaf(d1,d2,p12);
  }
  #pragma unroll
  for (int off=32; off>0; off>>=1){
    a0+=__shfl_down(a0,off); a1+=__shfl_down(a1,off); a2+=__shfl_down(a2,off);
    p00+=__shfl_down(p00,off); p11+=__shfl_down(p11,off); p22+=__shfl_down(p22,off);
    p01+=__shfl_down(p01,off); p02+=__shfl_down(p02,off); p12+=__shfl_down(p12,off);
  }
  if ((threadIdx.x & 63)==0){
    atomicAdd(&ls[0],a0); atomicAdd(&ls[1],a1); atomicAdd(&ls[2],a2);
    atomicAdd(&ls[3],p00); atomicAdd(&ls[4],p11); atomicAdd(&ls[5],p22);
    atomicAdd(&ls[6],p01); atomicAdd(&ls[7],p02); atomicAdd(&ls[8],p12);
  }
  __syncthreads();
  if (threadIdx.x < 9) atomicAdd(&est[threadIdx.x*16], ls[threadIdx.x]);  // one line per value
}

// ---- exclusive scan of degrees; writes running positions back into degcur ----
__global__ __launch_bounds__(1024) void k_scan(int* __restrict__ degcur,
    int* __restrict__ rs, int n)
{
  __shared__ int sm[1024];
  int t = threadIdx.x;
  int chunk = (n + 1023) >> 10;
  int b0 = t*chunk;
  int b1 = min(b0+chunk, n);
  int s = 0;
  for (int i=b0;i<b1;i++) s += degcur[i];
  sm[t] = s; __syncthreads();
  int acc = s;
  for (int off=1; off<1024; off<<=1){
    int v = (t>=off) ? sm[t-off] : 0;
    __syncthreads();
    acc += v;
    sm[t] = acc;
    __syncthreads();
  }
  int run = acc - s;
  for (int i=b0;i<b1;i++){ int d = degcur[i]; rs[i]=run; degcur[i]=run; run += d; }
  if (t==1023) rs[n] = acc;
}

// ---- scatter edges into dst-sorted order ----
__global__ __launch_bounds__(256) void k_scatter(const int* __restrict__ src,
    const int* __restrict__ dst, const float* __restrict__ ea, int E,
    int* __restrict__ cur, unsigned short* __restrict__ ss, float* __restrict__ eas)
{
  int tid = blockIdx.x*blockDim.x + threadIdx.x;
  int stride = gridDim.x*blockDim.x;
  for (int e=tid;e<E;e+=stride){
    int d = dst[e];
    int p = atomicAdd(&cur[d], 1);
    ss[p] = (unsigned short)src[e];
    eas[3*p+0] = ea[3*e+0];
    eas[3*p+1] = ea[3*e+1];
    eas[3*p+2] = ea[3*e+2];
  }
}

// ---- transpose the three 64x64 weight families ----
__global__ __launch_bounds__(256) void k_transp(const float* __restrict__ w2,
   const float* __restrict__ w1m, const float* __restrict__ w2m,
   float* __restrict__ w2t, float* __restrict__ w1mt, float* __restrict__ w2mt)
{
  int idx = blockIdx.x*256 + threadIdx.x;   // 3 * NL * 4096 total
  int f = idx >> 14;
  int r = idx & 16383;
  int l = r >> 12; int kc = r & 4095; int k = kc >> 6; int c = kc & 63;
  const float* s = (f==0)? w2 : (f==1)? w1m : w2m;
  float* o = (f==0)? w2t : (f==1)? w1mt : w2mt;
  o[l*4096 + c*64 + k] = s[l*4096 + k*64 + c];
}

// ---- fold edge-BN into affine A,c per layer/channel ----
__global__ __launch_bounds__(256) void k_prec(const float* __restrict__ est,
  const float* __restrict__ w1, const float* __restrict__ b1,
  const float* __restrict__ g1, const float* __restrict__ be1,
  float* __restrict__ ac, float invE)
{
  int t = threadIdx.x; int l = t>>6, c = t&63;
  float m0 = est[0]*invE, m1 = est[16]*invE, m2 = est[32]*invE;
  float c00 = est[48]*invE - m0*m0, c11 = est[64]*invE - m1*m1, c22 = est[80]*invE - m2*m2;
  float c01 = est[96]*invE - m0*m1, c02 = est[112]*invE - m0*m2, c12 = est[128]*invE - m1*m2;
  float w0 = w1[(l*3+0)*64+c], w1_ = w1[(l*3+1)*64+c], w2_ = w1[(l*3+2)*64+c];
  float b = b1[l*64+c], g = g1[l*64+c], be = be1[l*64+c];
  float mu = m0*w0 + m1*w1_ + m2*w2_ + b;
  float var = w0*w0*c00 + w1_*w1_*c11 + w2_*w2_*c22
            + 2.f*(w0*w1_*c01 + w0*w2_*c02 + w1_*w2_*c12);
  float sc = g * rsqrtf(var + EPS);
  float* o = ac + l*256 + c*4;
  o[0] = w0*sc; o[1] = w1_*sc; o[2] = w2_*sc; o[3] = (b - mu)*sc + be;
}

// ---- h0 = x @ lin_in_w + b  (4 threads per node, 16 ch each) ----
__global__ __launch_bounds__(256) void k_h0(const float* __restrict__ x,
  const float* __restrict__ w, const float* __restrict__ b, float* __restrict__ h, int n)
{
  int tid = blockIdx.x*256 + threadIdx.x;
  int i = tid >> 2; if (i>=n) return;
  int c0 = (tid & 3) << 4;
  float acc[16];
  #pragma unroll
  for (int j=0;j<16;j++) acc[j] = b[c0+j];
  const float* xr = x + (size_t)i*INDIM;
  for (int k=0;k<INDIM;k++){
    float xv = xr[k];
    const float* wr = w + k*EMB + c0;
    #pragma unroll
    for (int j=0;j<16;j++) acc[j] = fmaf(xv, wr[j], acc[j]);
  }
  float* hr = h + (size_t)i*EMB + c0;
  #pragma unroll
  for (int q=0;q<4;q++)
    *(float4*)(hr + 4*q) = make_float4(acc[4*q],acc[4*q+1],acc[4*q+2],acc[4*q+3]);
}

// ---- edge encoder sum, wave-per-node, lane=channel ----
__global__ __launch_bounds__(256) void k_edge(const int* __restrict__ rs,
  const float* __restrict__ eas, const float* __restrict__ ac,
  float* __restrict__ r, int n)
{
  int wv = (blockIdx.x*256 + threadIdx.x) >> 6;
  int lane = threadIdx.x & 63;
  if (wv >= n) return;
  float4 a = ((const float4*)ac)[lane];
  int e0 = rs[wv], e1 = rs[wv+1];
  float acc = 0.f;
  int e = e0;
  for (; e+4<=e1; e+=4){
    const float* ep = eas + (size_t)3*e;
    float d00=ep[0], d01=ep[1], d02=ep[2];
    float d10=ep[3], d11=ep[4], d12=ep[5];
    float d20=ep[6], d21=ep[7], d22=ep[8];
    float d30=ep[9], d31=ep[10], d32=ep[11];
    acc += fmaxf(fmaf(d00,a.x,fmaf(d01,a.y,fmaf(d02,a.z,a.w))),0.f);
    acc += fmaxf(fmaf(d10,a.x,fmaf(d11,a.y,fmaf(d12,a.z,a.w))),0.f);
    acc += fmaxf(fmaf(d20,a.x,fmaf(d21,a.y,fmaf(d22,a.z,a.w))),0.f);
    acc += fmaxf(fmaf(d30,a.x,fmaf(d31,a.y,fmaf(d32,a.z,a.w))),0.f);
  }
  for (; e<e1; e++){
    const float* ep = eas + (size_t)3*e;
    acc += fmaxf(fmaf(ep[0],a.x,fmaf(ep[1],a.y,fmaf(ep[2],a.z,a.w))),0.f);
  }
  r[(size_t)wv*EMB + lane] = acc;
}

// ---- neighbor gather, wave-per-node, lane=channel; z = hh[i] + sum hh[src] ----
__global__ __launch_bounds__(256) void k_gather(const float* __restrict__ hh,
  const int* __restrict__ rs, const unsigned short* __restrict__ ss,
  float* __restrict__ z, int n)
{
  int wv = (blockIdx.x*256 + threadIdx.x) >> 6;
  int lane = threadIdx.x & 63;
  if (wv >= n) return;
  int e0 = rs[wv], e1 = rs[wv+1];
  float acc = hh[(size_t)wv*EMB + lane];
  int e = e0;
  for (; e+4<=e1; e+=4){
    int s0=ss[e], s1=ss[e+1], s2=ss[e+2], s3=ss[e+3];
    acc += hh[(size_t)s0*EMB+lane];
    acc += hh[(size_t)s1*EMB+lane];
    acc += hh[(size_t)s2*EMB+lane];
    acc += hh[(size_t)s3*EMB+lane];
  }
  for (; e<e1; e++) acc += hh[(size_t)ss[e]*EMB+lane];
  z[(size_t)wv*EMB + lane] = acc;
}

// ---- hh = h(+bnrelu(y_prev)) + r@w2t + deg*b2 ; yhh aliases y(in)/hh(out) ----
__global__ __launch_bounds__(256) void k_m1(
  float* __restrict__ h, float* yhh, const float* __restrict__ r,
  const int* __restrict__ rs, const float* __restrict__ w2t, const float* __restrict__ b2,
  const float* __restrict__ st2, const float* __restrict__ g2, const float* __restrict__ be2,
  int n, int update, float invN)
{
  int tid = blockIdx.x*256 + threadIdx.x;
  int i = tid >> 2; if (i>=n) return;
  int c0 = (tid & 3) << 4;
  float rr[64];
  const float4* rp = (const float4*)(r + (size_t)i*EMB);
  #pragma unroll
  for (int q=0;q<16;q++){ float4 v=rp[q]; rr[4*q]=v.x; rr[4*q+1]=v.y; rr[4*q+2]=v.z; rr[4*q+3]=v.w; }
  float degf = (float)(rs[i+1]-rs[i]);
  float* hp = h + (size_t)i*EMB;
  float* yp = yhh + (size_t)i*EMB;
  #pragma unroll
  for (int g4=0; g4<4; g4++){
    int c = c0 + g4*4;
    float4 hv = *(const float4*)(hp + c);
    if (update){
      float4 yv = *(const float4*)(yp + c);
      hv.x += bnrelu(yv.x, st2[c+0], st2[64+c+0], g2[c+0], be2[c+0], invN);
      hv.y += bnrelu(yv.y, st2[c+1], st2[64+c+1], g2[c+1], be2[c+1], invN);
      hv.z += bnrelu(yv.z, st2[c+2], st2[64+c+2], g2[c+2], be2[c+2], invN);
      hv.w += bnrelu(yv.w, st2[c+3], st2[64+c+3], g2[c+3], be2[c+3], invN);
      *(float4*)(hp + c) = hv;
    }
    float o0 = fmaf(degf, b2[c+0], hv.x);
    float o1 = fmaf(degf, b2[c+1], hv.y);
    float o2 = fmaf(degf, b2[c+2], hv.z);
    float o3 = fmaf(degf, b2[c+3], hv.w);
    const float* wa = w2t + (c+0)*EMB;
    const float* wb = w2t + (c+1)*EMB;
    const float* wc = w2t + (c+2)*EMB;
    const float* wd = w2t + (c+3)*EMB;
    #pragma unroll
    for (int k=0;k<EMB;k++){
      float rk = rr[k];
      o0=fmaf(rk,wa[k],o0); o1=fmaf(rk,wb[k],o1); o2=fmaf(rk,wc[k],o2); o3=fmaf(rk,wd[k],o3);
    }
    *(float4*)(yp + c) = make_float4(o0,o1,o2,o3);
  }
}

// ---- y = z@w1t + b1 ----
__global__ __launch_bounds__(256) void k_m2(const float* __restrict__ z,
  const float* __restrict__ w1t, const float* __restrict__ b1,
  float* __restrict__ yhh, int n)
{
  int tid = blockIdx.x*256 + threadIdx.x;
  int i = tid >> 2; if (i>=n) return;
  int c0 = (tid & 3) << 4;
  float zz[64];
  const float4* zp = (const float4*)(z + (size_t)i*EMB);
  #pragma unroll
  for (int q=0;q<16;q++){ float4 v=zp[q]; zz[4*q]=v.x; zz[4*q+1]=v.y; zz[4*q+2]=v.z; zz[4*q+3]=v.w; }
  float* yp = yhh + (size_t)i*EMB;
  #pragma unroll
  for (int g4=0; g4<4; g4++){
    int c = c0 + g4*4;
    float o0=b1[c+0], o1=b1[c+1], o2=b1[c+2], o3=b1[c+3];
    const float* wa = w1t + (c+0)*EMB;
    const float* wb = w1t + (c+1)*EMB;
    const float* wc = w1t + (c+2)*EMB;
    const float* wd = w1t + (c+3)*EMB;
    #pragma unroll
    for (int k=0;k<EMB;k++){
      float zk = zz[k];
      o0=fmaf(zk,wa[k],o0); o1=fmaf(zk,wb[k],o1); o2=fmaf(zk,wc[k],o2); o3=fmaf(zk,wd[k],o3);
    }
    *(float4*)(yp + c) = make_float4(o0,o1,o2,o3);
  }
}

// ---- y = relu(bn1(y)) @ w2t + b2 (in place; wave-lockstep read-before-write) ----
__global__ __launch_bounds__(256) void k_m3(float* yhh,
  const float* __restrict__ st1, const float* __restrict__ g1, const float* __restrict__ be1,
  const float* __restrict__ w2t, const float* __restrict__ b2, int n, float invN)
{
  int tid = blockIdx.x*256 + threadIdx.x;
  int i = tid >> 2; if (i>=n) return;
  int c0 = (tid & 3) << 4;
  float t[64];
  const float4* yc = (const float4*)(yhh + (size_t)i*EMB);
  #pragma unroll
  for (int q=0;q<16;q++){
    float4 v = yc[q]; int c=4*q;
    t[c+0]=bnrelu(v.x, st1[c+0], st1[64+c+0], g1[c+0], be1[c+0], invN);
    t[c+1]=bnrelu(v.y, st1[c+1], st1[64+c+1], g1[c+1], be1[c+1], invN);
    t[c+2]=bnrelu(v.z, st1[c+2], st1[64+c+2], g1[c+2], be1[c+2], invN);
    t[c+3]=bnrelu(v.w, st1[c+3], st1[64+c+3], g1[c+3], be1[c+3], invN);
  }
  float* yp = yhh + (size_t)i*EMB;
  #pragma unroll
  for (int g4=0; g4<4; g4++){
    int c = c0 + g4*4;
    float o0=b2[c+0], o1=b2[c+1], o2=b2[c+2], o3=b2[c+3];
    const float* wa = w2t + (c+0)*EMB;
    const float* wb = w2t + (c+1)*EMB;
    const float* wc = w2t + (c+2)*EMB;
    const float* wd = w2t + (c+3)*EMB;
    #pragma unroll
    for (int k=0;k<EMB;k++){
      float tk = t[k];
      o0=fmaf(tk,wa[k],o0); o1=fmaf(tk,wb[k],o1); o2=fmaf(tk,wc[k],o2); o3=fmaf(tk,wd[k],o3);
    }
    *(float4*)(yp + c) = make_float4(o0,o1,o2,o3);
  }
}

// ---- per-channel sum/sumsq partials (no global atomics) ----
__global__ __launch_bounds__(256) void k_stats(const float* __restrict__ y,
    float* __restrict__ pst, int n)
{
  __shared__ float ls[128];
  int lane = threadIdx.x & 63;
  int wid  = threadIdx.x >> 6;
  int gw = blockIdx.x*4 + wid;
  int nw = gridDim.x*4;
  float s=0.f, q=0.f;
  for (int i=gw; i<n; i+=nw){
    float v = y[(size_t)i*EMB + lane];
    s += v; q = fmaf(v,v,q);
  }
  if (threadIdx.x < 128) ls[threadIdx.x] = 0.f;
  __syncthreads();
  atomicAdd(&ls[lane], s); atomicAdd(&ls[64+lane], q);
  __syncthreads();
  if (threadIdx.x < 128) pst[blockIdx.x*128 + threadIdx.x] = ls[threadIdx.x];
}

__global__ __launch_bounds__(128) void k_red(const float* __restrict__ pst,
    float* __restrict__ st, int nb)
{
  int t = threadIdx.x;
  float s = 0.f;
  for (int b=0;b<nb;b++) s += pst[b*128 + t];
  st[t] = s;
}

// ---- final: h4 = h3 + relu(bn2(y)); out = h4 . wp + bp ----
__global__ __launch_bounds__(256) void k_out(
  const float* __restrict__ h, const float* __restrict__ y,
  const float* __restrict__ st2, const float* __restrict__ g2, const float* __restrict__ be2,
  const float* __restrict__ wp, const float* __restrict__ bp,
  float* __restrict__ out, int n, float invN)
{
  int i = blockIdx.x*256 + threadIdx.x; if (i>=n) return;
  const float* hr = h + (size_t)i*EMB;
  const float* yr = y + (size_t)i*EMB;
  float acc = 0.f;
  #pragma unroll
  for (int q=0;q<16;q++){
    int c0=q*4;
    float4 hv = *(const float4*)(hr+c0);
    float4 yv = *(const float4*)(yr+c0);
    float f0 = hv.x + bnrelu(yv.x, st2[c0+0], st2[64+c0+0], g2[c0+0], be2[c0+0], invN);
    float f1 = hv.y + bnrelu(yv.y, st2[c0+1], st2[64+c0+1], g2[c0+1], be2[c0+1], invN);
    float f2 = hv.z + bnrelu(yv.z, st2[c0+2], st2[64+c0+2], g2[c0+2], be2[c0+2], invN);
    float f3 = hv.w + bnrelu(yv.w, st2[c0+3], st2[64+c0+3], g2[c0+3], be2[c0+3], invN);
    acc = fmaf(f0, wp[c0+0], acc);
    acc = fmaf(f1, wp[c0+1], acc);
    acc = fmaf(f2, wp[c0+2], acc);
    acc = fmaf(f3, wp[c0+3], acc);
  }
  out[i] = acc + bp[0];
}

extern "C" void kernel_launch(void* const* d_in, const int* in_sizes, int n_in,
                              void* d_out, int out_size, void* d_ws, size_t ws_size,
                              hipStream_t stream)
{
  const float* x        = (const float*)d_in[0];
  const int*   ei       = (const int*)d_in[1];
  const float* ea       = (const float*)d_in[2];
  const float* lin_in_w = (const float*)d_in[3];
  const float* lin_in_b = (const float*)d_in[4];
  const float* ee_w1    = (const float*)d_in[5];
  const float* ee_b1    = (const float*)d_in[6];
  const float* ee_g1    = (const float*)d_in[7];
  const float* ee_be1   = (const float*)d_in[8];
  const float* ee_w2    = (const float*)d_in[9];
  const float* ee_b2    = (const float*)d_in[10];
  const float* mlp_w1   = (const float*)d_in[11];
  const float* mlp_b1   = (const float*)d_in[12];
  const float* mlp_g1   = (const float*)d_in[13];
  const float* mlp_be1  = (const float*)d_in[14];
  const float* mlp_w2   = (const float*)d_in[15];
  const float* mlp_b2   = (const float*)d_in[16];
  const float* mlp_g2   = (const float*)d_in[17];
  const float* mlp_be2  = (const float*)d_in[18];
  const float* pred_w   = (const float*)d_in[19];
  const float* pred_b   = (const float*)d_in[20];

  int n = in_sizes[0] / INDIM;
  int E = in_sizes[1] / 2;
  const int* srcp = ei;
  const int* dstp = ei + E;

  char* w = (char*)d_ws;
  auto al = [](size_t o){ return (o + 255) & ~(size_t)255; };
  size_t o = 0;
  int*   deg = (int*)(w + o);  o += (size_t)n*4;  o = al(o);
  float* est = (float*)(w + o); o += 144*4;
  size_t zero_bytes = o;
  o = al(o); int* rs   = (int*)(w + o);   o += (size_t)(n+1)*4;
  o = al(o); unsigned short* ss = (unsigned short*)(w + o); o += (size_t)E*2;
  o = al(o); float* eas = (float*)(w + o); o += (size_t)E*12;
  o = al(o); float* acb = (float*)(w + o); o += (size_t)NL*256*4;
  o = al(o); float* w2t = (float*)(w + o); o += (size_t)NL*4096*4;
  o = al(o); float* w1mt= (float*)(w + o); o += (size_t)NL*4096*4;
  o = al(o); float* w2mt= (float*)(w + o); o += (size_t)NL*4096*4;
  o = al(o); float* h   = (float*)(w + o); o += (size_t)n*EMB*4;
  o = al(o); float* yhh = (float*)(w + o); o += (size_t)n*EMB*4;
  o = al(o); float* rz  = (float*)(w + o); o += (size_t)n*EMB*4;
  o = al(o); float* pst = (float*)(w + o); o += 128*128*4;
  o = al(o); float* nst = (float*)(w + o); o += (size_t)NL*256*4;

  (void)hipMemsetAsync(d_ws, 0, zero_bytes, stream);

  k_pass1<<<256, 256, 0, stream>>>(dstp, ea, E, deg, est);
  k_scan<<<1, 1024, 0, stream>>>(deg, rs, n);
  k_scatter<<<512, 256, 0, stream>>>(srcp, dstp, ea, E, deg /*cur*/, ss, eas);
  k_transp<<<192, 256, 0, stream>>>(ee_w2, mlp_w1, mlp_w2, w2t, w1mt, w2mt);
  k_prec<<<1, 256, 0, stream>>>(est, ee_w1, ee_b1, ee_g1, ee_be1, acb, 1.f/(float)E);

  int nb4 = (n*4 + 255)/256;   // 4 threads per node
  int nbw = (n + 3)/4;         // wave per node (4 waves/block)
  int nbn = (n + 255)/256;     // thread per node
  float invN = 1.f/(float)n;
  k_h0<<<nb4, 256, 0, stream>>>(x, lin_in_w, lin_in_b, h, n);

  for (int l=0; l<NL; l++){
    const float* st2p = (l>0) ? (nst + (size_t)(l-1)*256 + 128) : nst;
    const float* g2p  = (l>0) ? (mlp_g2  + (size_t)(l-1)*64) : mlp_g2;
    const float* be2p = (l>0) ? (mlp_be2 + (size_t)(l-1)*64) : mlp_be2;
    k_edge<<<nbw, 256, 0, stream>>>(rs, eas, acb + (size_t)l*256, rz, n);
    k_m1<<<nb4, 256, 0, stream>>>(h, yhh, rz, rs,
        w2t + (size_t)l*4096, ee_b2 + (size_t)l*64, st2p, g2p, be2p, n, (l>0)?1:0, invN);
    k_gather<<<nbw, 256, 0, stream>>>(yhh, rs, ss, rz, n);
    k_m2<<<nb4, 256, 0, stream>>>(rz, w1mt + (size_t)l*4096, mlp_b1 + (size_t)l*64, yhh, n);
    k_stats<<<128, 256, 0, stream>>>(yhh, pst, n);
    k_red<<<1, 128, 0, stream>>>(pst, nst + (size_t)l*256, 128);
    k_m3<<<nb4, 256, 0, stream>>>(yhh, nst + (size_t)l*256,
        mlp_g1 + (size_t)l*64, mlp_be1 + (size_t)l*64,
        w2mt + (size_t)l*4096, mlp_b2 + (size_t)l*64, n, invN);
    k_stats<<<128, 256, 0, stream>>>(yhh, pst, n);
    k_red<<<1, 128, 0, stream>>>(pst, nst + (size_t)l*256 + 128, 128);
  }
  k_out<<<nbn, 256, 0, stream>>>(h, yhh,
      nst + (size_t)(NL-1)*256 + 128, mlp_g2 + (size_t)(NL-1)*64, mlp_be2 + (size_t)(NL-1)*64,
      pred_w, pred_b, (float*)d_out, n, invN);
}

// Round 3
// 1579.167 us; speedup vs baseline: 1.7822x; 1.7822x over previous
//
#include <hip/hip_runtime.h>

#define EMB 64
#define INDIM 140
#define NL 4
#define EPS 1e-5f

__device__ __forceinline__ float bnrelu(float v, float sum, float sq, float g, float be, float invN){
  float mu  = sum*invN;
  float var = fmaf(-mu, mu, sq*invN);
  float sc  = g * rsqrtf(var + EPS);
  return fmaxf(fmaf(v - mu, sc, be), 0.f);
}

// ---- fused: deg histogram + edge_attr moments (block-reduced, padded atomics) ----
__global__ __launch_bounds__(256) void k_pass1(const int* __restrict__ dst,
    const float* __restrict__ ea, int E, int* __restrict__ deg, float* __restrict__ est)
{
  __shared__ float ls[9];
  if (threadIdx.x < 9) ls[threadIdx.x] = 0.f;
  __syncthreads();
  int tid = blockIdx.x*blockDim.x + threadIdx.x;
  int stride = gridDim.x*blockDim.x;
  float a0=0,a1=0,a2=0,p00=0,p11=0,p22=0,p01=0,p02=0,p12=0;
  for (int e=tid;e<E;e+=stride){
    atomicAdd(&deg[dst[e]],1);
    float d0=ea[3*e+0], d1=ea[3*e+1], d2=ea[3*e+2];
    a0+=d0;a1+=d1;a2+=d2;
    p00=fmaf(d0,d0,p00); p11=fmaf(d1,d1,p11); p22=fmaf(d2,d2,p22);
    p01=fmaf(d0,d1,p01); p02=fmaf(d0,d2,p02); p12=fmaf(d1,d2,p12);
  }
  #pragma unroll
  for (int off=32; off>0; off>>=1){
    a0+=__shfl_down(a0,off); a1+=__shfl_down(a1,off); a2+=__shfl_down(a2,off);
    p00+=__shfl_down(p00,off); p11+=__shfl_down(p11,off); p22+=__shfl_down(p22,off);
    p01+=__shfl_down(p01,off); p02+=__shfl_down(p02,off); p12+=__shfl_down(p12,off);
  }
  if ((threadIdx.x & 63)==0){
    atomicAdd(&ls[0],a0); atomicAdd(&ls[1],a1); atomicAdd(&ls[2],a2);
    atomicAdd(&ls[3],p00); atomicAdd(&ls[4],p11); atomicAdd(&ls[5],p22);
    atomicAdd(&ls[6],p01); atomicAdd(&ls[7],p02); atomicAdd(&ls[8],p12);
  }
  __syncthreads();
  if (threadIdx.x < 9) atomicAdd(&est[threadIdx.x*16], ls[threadIdx.x]);  // one line per value
}

// ---- exclusive scan of degrees; writes running positions back into degcur ----
__global__ __launch_bounds__(1024) void k_scan(int* __restrict__ degcur,
    int* __restrict__ rs, int n)
{
  __shared__ int sm[1024];
  int t = threadIdx.x;
  int chunk = (n + 1023) >> 10;
  int b0 = t*chunk;
  int b1 = min(b0+chunk, n);
  int s = 0;
  for (int i=b0;i<b1;i++) s += degcur[i];
  sm[t] = s; __syncthreads();
  int acc = s;
  for (int off=1; off<1024; off<<=1){
    int v = (t>=off) ? sm[t-off] : 0;
    __syncthreads();
    acc += v;
    sm[t] = acc;
    __syncthreads();
  }
  int run = acc - s;
  for (int i=b0;i<b1;i++){ int d = degcur[i]; rs[i]=run; degcur[i]=run; run += d; }
  if (t==1023) rs[n] = acc;
}

// ---- scatter edges into dst-sorted order ----
__global__ __launch_bounds__(256) void k_scatter(const int* __restrict__ src,
    const int* __restrict__ dst, const float* __restrict__ ea, int E,
    int* __restrict__ cur, unsigned short* __restrict__ ss, float* __restrict__ eas)
{
  int tid = blockIdx.x*blockDim.x + threadIdx.x;
  int stride = gridDim.x*blockDim.x;
  for (int e=tid;e<E;e+=stride){
    int d = dst[e];
    int p = atomicAdd(&cur[d], 1);
    ss[p] = (unsigned short)src[e];
    eas[3*p+0] = ea[3*e+0];
    eas[3*p+1] = ea[3*e+1];
    eas[3*p+2] = ea[3*e+2];
  }
}

// ---- fold edge-BN into affine A,c per layer/channel ----
__global__ __launch_bounds__(256) void k_prec(const float* __restrict__ est,
  const float* __restrict__ w1, const float* __restrict__ b1,
  const float* __restrict__ g1, const float* __restrict__ be1,
  float* __restrict__ ac, float invE)
{
  int t = threadIdx.x; int l = t>>6, c = t&63;
  float m0 = est[0]*invE, m1 = est[16]*invE, m2 = est[32]*invE;
  float c00 = est[48]*invE - m0*m0, c11 = est[64]*invE - m1*m1, c22 = est[80]*invE - m2*m2;
  float c01 = est[96]*invE - m0*m1, c02 = est[112]*invE - m0*m2, c12 = est[128]*invE - m1*m2;
  float w0 = w1[(l*3+0)*64+c], w1_ = w1[(l*3+1)*64+c], w2_ = w1[(l*3+2)*64+c];
  float b = b1[l*64+c], g = g1[l*64+c], be = be1[l*64+c];
  float mu = m0*w0 + m1*w1_ + m2*w2_ + b;
  float var = w0*w0*c00 + w1_*w1_*c11 + w2_*w2_*c22
            + 2.f*(w0*w1_*c01 + w0*w2_*c02 + w1_*w2_*c12);
  float sc = g * rsqrtf(var + EPS);
  float* o = ac + l*256 + c*4;
  o[0] = w0*sc; o[1] = w1_*sc; o[2] = w2_*sc; o[3] = (b - mu)*sc + be;
}

// ---- h0 = x @ lin_in_w + b  (thread-per-node, k-chunked, uniform weight rows) ----
__global__ __launch_bounds__(64,1) void k_h0(const float* __restrict__ x,
  const float* __restrict__ w, const float* __restrict__ b, float* __restrict__ h, int n)
{
  int i = blockIdx.x*64 + threadIdx.x; if (i>=n) return;
  float acc[EMB];
  #pragma unroll
  for (int c=0;c<EMB;c++) acc[c] = b[c];
  const float4* xp = (const float4*)(x + (size_t)i*INDIM);
  for (int kb=0; kb<INDIM/4; kb++){
    float4 xv = xp[kb];
    const float* wr = w + kb*4*EMB;
    #pragma unroll
    for (int q=0;q<16;q++){
      float4 w0 = *(const float4*)(wr + 4*q);
      float4 w1 = *(const float4*)(wr + EMB + 4*q);
      float4 w2 = *(const float4*)(wr + 2*EMB + 4*q);
      float4 w3 = *(const float4*)(wr + 3*EMB + 4*q);
      int c = 4*q;
      acc[c+0]=fmaf(xv.x,w0.x,fmaf(xv.y,w1.x,fmaf(xv.z,w2.x,fmaf(xv.w,w3.x,acc[c+0]))));
      acc[c+1]=fmaf(xv.x,w0.y,fmaf(xv.y,w1.y,fmaf(xv.z,w2.y,fmaf(xv.w,w3.y,acc[c+1]))));
      acc[c+2]=fmaf(xv.x,w0.z,fmaf(xv.y,w1.z,fmaf(xv.z,w2.z,fmaf(xv.w,w3.z,acc[c+2]))));
      acc[c+3]=fmaf(xv.x,w0.w,fmaf(xv.y,w1.w,fmaf(xv.z,w2.w,fmaf(xv.w,w3.w,acc[c+3]))));
    }
  }
  float* hr = h + (size_t)i*EMB;
  #pragma unroll
  for (int q=0;q<16;q++)
    *(float4*)(hr + 4*q) = make_float4(acc[4*q],acc[4*q+1],acc[4*q+2],acc[4*q+3]);
}

// ---- edge encoder sum, wave-per-node, lane=channel ----
__global__ __launch_bounds__(256) void k_edge(const int* __restrict__ rs,
  const float* __restrict__ eas, const float* __restrict__ ac,
  float* __restrict__ r, int n)
{
  int wv = (blockIdx.x*256 + threadIdx.x) >> 6;
  int lane = threadIdx.x & 63;
  if (wv >= n) return;
  float4 a = ((const float4*)ac)[lane];
  int e0 = rs[wv], e1 = rs[wv+1];
  float acc = 0.f;
  int e = e0;
  for (; e+4<=e1; e+=4){
    const float* ep = eas + (size_t)3*e;
    float d00=ep[0], d01=ep[1], d02=ep[2];
    float d10=ep[3], d11=ep[4], d12=ep[5];
    float d20=ep[6], d21=ep[7], d22=ep[8];
    float d30=ep[9], d31=ep[10], d32=ep[11];
    acc += fmaxf(fmaf(d00,a.x,fmaf(d01,a.y,fmaf(d02,a.z,a.w))),0.f);
    acc += fmaxf(fmaf(d10,a.x,fmaf(d11,a.y,fmaf(d12,a.z,a.w))),0.f);
    acc += fmaxf(fmaf(d20,a.x,fmaf(d21,a.y,fmaf(d22,a.z,a.w))),0.f);
    acc += fmaxf(fmaf(d30,a.x,fmaf(d31,a.y,fmaf(d32,a.z,a.w))),0.f);
  }
  for (; e<e1; e++){
    const float* ep = eas + (size_t)3*e;
    acc += fmaxf(fmaf(ep[0],a.x,fmaf(ep[1],a.y,fmaf(ep[2],a.z,a.w))),0.f);
  }
  r[(size_t)wv*EMB + lane] = acc;
}

// ---- neighbor gather, wave-per-node, lane=channel; z = hh[i] + sum hh[src] ----
__global__ __launch_bounds__(256) void k_gather(const float* __restrict__ hh,
  const int* __restrict__ rs, const unsigned short* __restrict__ ss,
  float* __restrict__ z, int n)
{
  int wv = (blockIdx.x*256 + threadIdx.x) >> 6;
  int lane = threadIdx.x & 63;
  if (wv >= n) return;
  int e0 = rs[wv], e1 = rs[wv+1];
  float acc = hh[(size_t)wv*EMB + lane];
  int e = e0;
  for (; e+4<=e1; e+=4){
    int s0=ss[e], s1=ss[e+1], s2=ss[e+2], s3=ss[e+3];
    acc += hh[(size_t)s0*EMB+lane];
    acc += hh[(size_t)s1*EMB+lane];
    acc += hh[(size_t)s2*EMB+lane];
    acc += hh[(size_t)s3*EMB+lane];
  }
  for (; e<e1; e++) acc += hh[(size_t)ss[e]*EMB+lane];
  z[(size_t)wv*EMB + lane] = acc;
}

// ---- hh = h(+bnrelu(y_prev)) + r@w2 + deg*b2 (thread-per-node) ----
__global__ __launch_bounds__(64,1) void km1(
  float* __restrict__ h, float* __restrict__ yhh, const float* __restrict__ r,
  const int* __restrict__ rs, const float* __restrict__ w2, const float* __restrict__ b2,
  const float* __restrict__ st2, const float* __restrict__ g2, const float* __restrict__ be2,
  int n, int update, float invN)
{
  int i = blockIdx.x*64 + threadIdx.x; if (i>=n) return;
  float degf = (float)(rs[i+1]-rs[i]);
  float* hp = h + (size_t)i*EMB;
  float* yp = yhh + (size_t)i*EMB;
  float acc[EMB];
  if (update){
    #pragma unroll
    for (int q=0;q<16;q++){
      int c = 4*q;
      float4 hv = *(const float4*)(hp+c);
      float4 yv = *(const float4*)(yp+c);
      hv.x += bnrelu(yv.x, st2[c+0], st2[64+c+0], g2[c+0], be2[c+0], invN);
      hv.y += bnrelu(yv.y, st2[c+1], st2[64+c+1], g2[c+1], be2[c+1], invN);
      hv.z += bnrelu(yv.z, st2[c+2], st2[64+c+2], g2[c+2], be2[c+2], invN);
      hv.w += bnrelu(yv.w, st2[c+3], st2[64+c+3], g2[c+3], be2[c+3], invN);
      *(float4*)(hp+c) = hv;
      acc[c+0]=fmaf(degf,b2[c+0],hv.x); acc[c+1]=fmaf(degf,b2[c+1],hv.y);
      acc[c+2]=fmaf(degf,b2[c+2],hv.z); acc[c+3]=fmaf(degf,b2[c+3],hv.w);
    }
  } else {
    #pragma unroll
    for (int q=0;q<16;q++){
      int c = 4*q;
      float4 hv = *(const float4*)(hp+c);
      acc[c+0]=fmaf(degf,b2[c+0],hv.x); acc[c+1]=fmaf(degf,b2[c+1],hv.y);
      acc[c+2]=fmaf(degf,b2[c+2],hv.z); acc[c+3]=fmaf(degf,b2[c+3],hv.w);
    }
  }
  const float4* rp = (const float4*)(r + (size_t)i*EMB);
  for (int kb=0; kb<EMB/4; kb++){
    float4 xv = rp[kb];
    const float* wr = w2 + kb*4*EMB;
    #pragma unroll
    for (int q=0;q<16;q++){
      float4 w0 = *(const float4*)(wr + 4*q);
      float4 w1 = *(const float4*)(wr + EMB + 4*q);
      float4 w2v= *(const float4*)(wr + 2*EMB + 4*q);
      float4 w3 = *(const float4*)(wr + 3*EMB + 4*q);
      int c = 4*q;
      acc[c+0]=fmaf(xv.x,w0.x,fmaf(xv.y,w1.x,fmaf(xv.z,w2v.x,fmaf(xv.w,w3.x,acc[c+0]))));
      acc[c+1]=fmaf(xv.x,w0.y,fmaf(xv.y,w1.y,fmaf(xv.z,w2v.y,fmaf(xv.w,w3.y,acc[c+1]))));
      acc[c+2]=fmaf(xv.x,w0.z,fmaf(xv.y,w1.z,fmaf(xv.z,w2v.z,fmaf(xv.w,w3.z,acc[c+2]))));
      acc[c+3]=fmaf(xv.x,w0.w,fmaf(xv.y,w1.w,fmaf(xv.z,w2v.w,fmaf(xv.w,w3.w,acc[c+3]))));
    }
  }
  #pragma unroll
  for (int q=0;q<16;q++)
    *(float4*)(yp + 4*q) = make_float4(acc[4*q],acc[4*q+1],acc[4*q+2],acc[4*q+3]);
}

// ---- y = z@w1 + b1 (thread-per-node) ----
__global__ __launch_bounds__(64,1) void km2(const float* __restrict__ z,
  const float* __restrict__ w1, const float* __restrict__ b1,
  float* __restrict__ yhh, int n)
{
  int i = blockIdx.x*64 + threadIdx.x; if (i>=n) return;
  float acc[EMB];
  #pragma unroll
  for (int c=0;c<EMB;c++) acc[c] = b1[c];
  const float4* zp = (const float4*)(z + (size_t)i*EMB);
  for (int kb=0; kb<EMB/4; kb++){
    float4 xv = zp[kb];
    const float* wr = w1 + kb*4*EMB;
    #pragma unroll
    for (int q=0;q<16;q++){
      float4 w0 = *(const float4*)(wr + 4*q);
      float4 w1v= *(const float4*)(wr + EMB + 4*q);
      float4 w2v= *(const float4*)(wr + 2*EMB + 4*q);
      float4 w3 = *(const float4*)(wr + 3*EMB + 4*q);
      int c = 4*q;
      acc[c+0]=fmaf(xv.x,w0.x,fmaf(xv.y,w1v.x,fmaf(xv.z,w2v.x,fmaf(xv.w,w3.x,acc[c+0]))));
      acc[c+1]=fmaf(xv.x,w0.y,fmaf(xv.y,w1v.y,fmaf(xv.z,w2v.y,fmaf(xv.w,w3.y,acc[c+1]))));
      acc[c+2]=fmaf(xv.x,w0.z,fmaf(xv.y,w1v.z,fmaf(xv.z,w2v.z,fmaf(xv.w,w3.z,acc[c+2]))));
      acc[c+3]=fmaf(xv.x,w0.w,fmaf(xv.y,w1v.w,fmaf(xv.z,w2v.w,fmaf(xv.w,w3.w,acc[c+3]))));
    }
  }
  float* yp = yhh + (size_t)i*EMB;
  #pragma unroll
  for (int q=0;q<16;q++)
    *(float4*)(yp + 4*q) = make_float4(acc[4*q],acc[4*q+1],acc[4*q+2],acc[4*q+3]);
}

// ---- y = relu(bn1(y)) @ w2m + b2 (thread-per-node, in place) ----
__global__ __launch_bounds__(64,1) void km3(float* __restrict__ yhh,
  const float* __restrict__ st1, const float* __restrict__ g1, const float* __restrict__ be1,
  const float* __restrict__ w2, const float* __restrict__ b2, int n, float invN)
{
  int i = blockIdx.x*64 + threadIdx.x; if (i>=n) return;
  float* yp = yhh + (size_t)i*EMB;
  float t[EMB];
  #pragma unroll
  for (int q=0;q<16;q++){
    int c = 4*q;
    float4 v = *(const float4*)(yp + c);
    t[c+0]=bnrelu(v.x, st1[c+0], st1[64+c+0], g1[c+0], be1[c+0], invN);
    t[c+1]=bnrelu(v.y, st1[c+1], st1[64+c+1], g1[c+1], be1[c+1], invN);
    t[c+2]=bnrelu(v.z, st1[c+2], st1[64+c+2], g1[c+2], be1[c+2], invN);
    t[c+3]=bnrelu(v.w, st1[c+3], st1[64+c+3], g1[c+3], be1[c+3], invN);
  }
  float acc[EMB];
  #pragma unroll
  for (int c=0;c<EMB;c++) acc[c] = b2[c];
  #pragma unroll
  for (int kb=0; kb<EMB/4; kb++){
    const float* wr = w2 + kb*4*EMB;
    float x0=t[4*kb], x1=t[4*kb+1], x2=t[4*kb+2], x3=t[4*kb+3];
    #pragma unroll
    for (int q=0;q<16;q++){
      float4 w0 = *(const float4*)(wr + 4*q);
      float4 w1v= *(const float4*)(wr + EMB + 4*q);
      float4 w2v= *(const float4*)(wr + 2*EMB + 4*q);
      float4 w3 = *(const float4*)(wr + 3*EMB + 4*q);
      int c = 4*q;
      acc[c+0]=fmaf(x0,w0.x,fmaf(x1,w1v.x,fmaf(x2,w2v.x,fmaf(x3,w3.x,acc[c+0]))));
      acc[c+1]=fmaf(x0,w0.y,fmaf(x1,w1v.y,fmaf(x2,w2v.y,fmaf(x3,w3.y,acc[c+1]))));
      acc[c+2]=fmaf(x0,w0.z,fmaf(x1,w1v.z,fmaf(x2,w2v.z,fmaf(x3,w3.z,acc[c+2]))));
      acc[c+3]=fmaf(x0,w0.w,fmaf(x1,w1v.w,fmaf(x2,w2v.w,fmaf(x3,w3.w,acc[c+3]))));
    }
  }
  #pragma unroll
  for (int q=0;q<16;q++)
    *(float4*)(yp + 4*q) = make_float4(acc[4*q],acc[4*q+1],acc[4*q+2],acc[4*q+3]);
}

// ---- per-channel sum/sumsq partials (no global atomics) ----
__global__ __launch_bounds__(256) void k_stats(const float* __restrict__ y,
    float* __restrict__ pst, int n)
{
  __shared__ float ls[128];
  int lane = threadIdx.x & 63;
  int wid  = threadIdx.x >> 6;
  int gw = blockIdx.x*4 + wid;
  int nw = gridDim.x*4;
  float s=0.f, q=0.f;
  for (int i=gw; i<n; i+=nw){
    float v = y[(size_t)i*EMB + lane];
    s += v; q = fmaf(v,v,q);
  }
  if (threadIdx.x < 128) ls[threadIdx.x] = 0.f;
  __syncthreads();
  atomicAdd(&ls[lane], s); atomicAdd(&ls[64+lane], q);
  __syncthreads();
  if (threadIdx.x < 128) pst[blockIdx.x*128 + threadIdx.x] = ls[threadIdx.x];
}

__global__ __launch_bounds__(128) void k_red(const float* __restrict__ pst,
    float* __restrict__ st, int nb)
{
  int t = threadIdx.x;
  float s = 0.f;
  for (int b=0;b<nb;b++) s += pst[b*128 + t];
  st[t] = s;
}

// ---- final: h4 = h3 + relu(bn2(y)); out = h4 . wp + bp ----
__global__ __launch_bounds__(256) void k_out(
  const float* __restrict__ h, const float* __restrict__ y,
  const float* __restrict__ st2, const float* __restrict__ g2, const float* __restrict__ be2,
  const float* __restrict__ wp, const float* __restrict__ bp,
  float* __restrict__ out, int n, float invN)
{
  int i = blockIdx.x*256 + threadIdx.x; if (i>=n) return;
  const float* hr = h + (size_t)i*EMB;
  const float* yr = y + (size_t)i*EMB;
  float acc = 0.f;
  #pragma unroll
  for (int q=0;q<16;q++){
    int c0=q*4;
    float4 hv = *(const float4*)(hr+c0);
    float4 yv = *(const float4*)(yr+c0);
    float f0 = hv.x + bnrelu(yv.x, st2[c0+0], st2[64+c0+0], g2[c0+0], be2[c0+0], invN);
    float f1 = hv.y + bnrelu(yv.y, st2[c0+1], st2[64+c0+1], g2[c0+1], be2[c0+1], invN);
    float f2 = hv.z + bnrelu(yv.z, st2[c0+2], st2[64+c0+2], g2[c0+2], be2[c0+2], invN);
    float f3 = hv.w + bnrelu(yv.w, st2[c0+3], st2[64+c0+3], g2[c0+3], be2[c0+3], invN);
    acc = fmaf(f0, wp[c0+0], acc);
    acc = fmaf(f1, wp[c0+1], acc);
    acc = fmaf(f2, wp[c0+2], acc);
    acc = fmaf(f3, wp[c0+3], acc);
  }
  out[i] = acc + bp[0];
}

extern "C" void kernel_launch(void* const* d_in, const int* in_sizes, int n_in,
                              void* d_out, int out_size, void* d_ws, size_t ws_size,
                              hipStream_t stream)
{
  const float* x        = (const float*)d_in[0];
  const int*   ei       = (const int*)d_in[1];
  const float* ea       = (const float*)d_in[2];
  const float* lin_in_w = (const float*)d_in[3];
  const float* lin_in_b = (const float*)d_in[4];
  const float* ee_w1    = (const float*)d_in[5];
  const float* ee_b1    = (const float*)d_in[6];
  const float* ee_g1    = (const float*)d_in[7];
  const float* ee_be1   = (const float*)d_in[8];
  const float* ee_w2    = (const float*)d_in[9];
  const float* ee_b2    = (const float*)d_in[10];
  const float* mlp_w1   = (const float*)d_in[11];
  const float* mlp_b1   = (const float*)d_in[12];
  const float* mlp_g1   = (const float*)d_in[13];
  const float* mlp_be1  = (const float*)d_in[14];
  const float* mlp_w2   = (const float*)d_in[15];
  const float* mlp_b2   = (const float*)d_in[16];
  const float* mlp_g2   = (const float*)d_in[17];
  const float* mlp_be2  = (const float*)d_in[18];
  const float* pred_w   = (const float*)d_in[19];
  const float* pred_b   = (const float*)d_in[20];

  int n = in_sizes[0] / INDIM;
  int E = in_sizes[1] / 2;
  const int* srcp = ei;
  const int* dstp = ei + E;

  char* w = (char*)d_ws;
  auto al = [](size_t o){ return (o + 255) & ~(size_t)255; };
  size_t o = 0;
  int*   deg = (int*)(w + o);  o += (size_t)n*4;  o = al(o);
  float* est = (float*)(w + o); o += 144*4;
  size_t zero_bytes = o;
  o = al(o); int* rs   = (int*)(w + o);   o += (size_t)(n+1)*4;
  o = al(o); unsigned short* ss = (unsigned short*)(w + o); o += (size_t)E*2;
  o = al(o); float* eas = (float*)(w + o); o += (size_t)E*12;
  o = al(o); float* acb = (float*)(w + o); o += (size_t)NL*256*4;
  o = al(o); float* h   = (float*)(w + o); o += (size_t)n*EMB*4;
  o = al(o); float* yhh = (float*)(w + o); o += (size_t)n*EMB*4;
  o = al(o); float* rz  = (float*)(w + o); o += (size_t)n*EMB*4;
  o = al(o); float* pst = (float*)(w + o); o += 128*128*4;
  o = al(o); float* nst = (float*)(w + o); o += (size_t)NL*256*4;

  (void)hipMemsetAsync(d_ws, 0, zero_bytes, stream);

  k_pass1<<<256, 256, 0, stream>>>(dstp, ea, E, deg, est);
  k_scan<<<1, 1024, 0, stream>>>(deg, rs, n);
  k_scatter<<<512, 256, 0, stream>>>(srcp, dstp, ea, E, deg /*cur*/, ss, eas);
  k_prec<<<1, 256, 0, stream>>>(est, ee_w1, ee_b1, ee_g1, ee_be1, acb, 1.f/(float)E);

  int nb64 = (n + 63)/64;      // thread-per-node, 64-thread blocks
  int nbw  = (n + 3)/4;        // wave per node (4 waves/block)
  int nbn  = (n + 255)/256;    // thread per node, 256-thread blocks
  float invN = 1.f/(float)n;
  k_h0<<<nb64, 64, 0, stream>>>(x, lin_in_w, lin_in_b, h, n);

  for (int l=0; l<NL; l++){
    const float* st2p = (l>0) ? (nst + (size_t)(l-1)*256 + 128) : nst;
    const float* g2p  = (l>0) ? (mlp_g2  + (size_t)(l-1)*64) : mlp_g2;
    const float* be2p = (l>0) ? (mlp_be2 + (size_t)(l-1)*64) : mlp_be2;
    k_edge<<<nbw, 256, 0, stream>>>(rs, eas, acb + (size_t)l*256, rz, n);
    km1<<<nb64, 64, 0, stream>>>(h, yhh, rz, rs,
        ee_w2 + (size_t)l*4096, ee_b2 + (size_t)l*64, st2p, g2p, be2p, n, (l>0)?1:0, invN);
    k_gather<<<nbw, 256, 0, stream>>>(yhh, rs, ss, rz, n);
    km2<<<nb64, 64, 0, stream>>>(rz, mlp_w1 + (size_t)l*4096, mlp_b1 + (size_t)l*64, yhh, n);
    k_stats<<<128, 256, 0, stream>>>(yhh, pst, n);
    k_red<<<1, 128, 0, stream>>>(pst, nst + (size_t)l*256, 128);
    km3<<<nb64, 64, 0, stream>>>(yhh, nst + (size_t)l*256,
        mlp_g1 + (size_t)l*64, mlp_be1 + (size_t)l*64,
        mlp_w2 + (size_t)l*4096, mlp_b2 + (size_t)l*64, n, invN);
    k_stats<<<128, 256, 0, stream>>>(yhh, pst, n);
    k_red<<<1, 128, 0, stream>>>(pst, nst + (size_t)l*256 + 128, 128);
  }
  k_out<<<nbn, 256, 0, stream>>>(h, yhh,
      nst + (size_t)(NL-1)*256 + 128, mlp_g2 + (size_t)(NL-1)*64, mlp_be2 + (size_t)(NL-1)*64,
      pred_w, pred_b, (float*)d_out, n, invN);
}